// Round 4
// baseline (343.470 us; speedup 1.0000x reference)
//
#include <hip/hip_runtime.h>

// PointConv: B=4, N=16384, K=32, F=64
// out[p,f] = sum_k ( lrelu(rel(p,k) @ W1 + b1) @ W2 + b2 )[f] * x[idx[p,k], f]
//
// Round 4: f16 everywhere in the matmul path, instruction-count attack.
//  - h computed as half2 pairs via v_pk_fma_f16 (W1/b1 pre-paired in LDS)
//  - v_mfma_f32_32x32x16_f16, two f-interleaved 32-col tiles: tile c <-> f=2m+c
//    -> x gather becomes ONE float2 load per (reg), out store one float2
//  - epilogue neighbor rows via readfirstlane(p) + uniform idx row -> s_load
//    into SGPRs (replaces ds_bpermute shuffles)
//  - b2 folded into accumulator init (acc = b2[f])
//  - __launch_bounds__(256,4): cap VGPR at 128, no spills (live set ~118)

#define NPTS   16384
#define KNB    32
#define F      64
#define BATCH  4
#define LOG2N  14
#define WPTS   4

typedef _Float16 h2     __attribute__((ext_vector_type(2)));
typedef _Float16 h8     __attribute__((ext_vector_type(8)));
typedef float    f32x16 __attribute__((ext_vector_type(16)));

__global__ __launch_bounds__(256, 4) void pointconv_mfma(
    const float* __restrict__ x,
    const float* __restrict__ pos,
    const int*   __restrict__ idx,
    const float* __restrict__ W1,
    const float* __restrict__ b1,
    const float* __restrict__ W2,
    const float* __restrict__ b2,
    float*       __restrict__ out)
{
    // w1p[g/2] = {wx[g],wx[g+1], wy[g],wy[g+1], wz[g],wz[g+1], b1[g],b1[g+1]} (f16)
    __shared__ __align__(16) _Float16 w1p[32][8];
    // w2h[f][g] = f16(W2[g][f]), pad 72 (stride 144 B keeps b128 reads 16B-aligned)
    __shared__ __align__(16) _Float16 w2h[F][72];

    const int tid = threadIdx.x;
    if (tid < 32) {
        const int g = 2 * tid;
        w1p[tid][0] = (_Float16)W1[0 * F + g]; w1p[tid][1] = (_Float16)W1[0 * F + g + 1];
        w1p[tid][2] = (_Float16)W1[1 * F + g]; w1p[tid][3] = (_Float16)W1[1 * F + g + 1];
        w1p[tid][4] = (_Float16)W1[2 * F + g]; w1p[tid][5] = (_Float16)W1[2 * F + g + 1];
        w1p[tid][6] = (_Float16)b1[g];         w1p[tid][7] = (_Float16)b1[g + 1];
    }
#pragma unroll
    for (int r = 0; r < 16; ++r) {             // 4096 elems, coalesced global read
        const int e = r * 256 + tid;           // e = g*64 + f
        w2h[e & 63][e >> 6] = (_Float16)W2[e];
    }
    __syncthreads();

    const int lane = tid & 63;
    const int wv   = tid >> 6;
    const int m    = lane & 31;   // MFMA row (neighbor slot) / col within 32-tile
    const int hf   = lane >> 5;   // k-half of A/B fragments

    // B fragments: bfrag[t][c][j] = f16(W2[16t+8*hf+j][2m+c])
    h8 bfrag[4][2];
#pragma unroll
    for (int t = 0; t < 4; ++t)
#pragma unroll
        for (int c = 0; c < 2; ++c)
            bfrag[t][c] = *(const h8*)&w2h[2 * m + c][16 * t + 8 * hf];

    const float2 b2v = *(const float2*)(b2 + 2 * m);

    const int p0   = (blockIdx.x * 4 + wv) * WPTS;
    const int base = (p0 >> LOG2N) << LOG2N;           // b*N, same for all WPTS points
    const float* __restrict__ xb2 = x + (size_t)base * F + 2 * m;  // lane's gather base

    // ---- stage 1: vector idx (lane m owns neighbor m), coalesced ----
    int jm[WPTS];
#pragma unroll
    for (int i = 0; i < WPTS; ++i) jm[i] = idx[(p0 + i) * KNB + m];

    // ---- stage 2: rel_pos for all points ----
    float rx[WPTS], ry[WPTS], rz[WPTS];
#pragma unroll
    for (int i = 0; i < WPTS; ++i) {
        const int p = p0 + i;
        const float px = pos[p * 3 + 0];
        const float py = pos[p * 3 + 1];
        const float pz = pos[p * 3 + 2];
        const int nr = base + jm[i];
        rx[i] = px - pos[nr * 3 + 0];
        ry[i] = py - pos[nr * 3 + 1];
        rz[i] = pz - pos[nr * 3 + 2];
    }

    const h2 c01 = { (_Float16)0.1f, (_Float16)0.1f };

    // ---- stage 3: per point ----
#pragma unroll
    for (int i = 0; i < WPTS; ++i) {
        const int p   = p0 + i;
        const int p_s = __builtin_amdgcn_readfirstlane(p);       // wave-uniform
        const int* __restrict__ rowp = idx + (size_t)p_s * KNB;
        int js[KNB];
#pragma unroll
        for (int c = 0; c < KNB; ++c) js[c] = rowp[c];           // s_load -> SGPRs

        // 3a: x-gather (float2, depends only on idx) — lands during h/MFMA
        float2 xv[16];
#pragma unroll
        for (int reg = 0; reg < 16; ++reg) {
            const int rA = (reg & 3) + ((reg >> 2) << 3);        // row for hf=0
            const int jk = hf ? js[rA + 4] : js[rA];
            xv[reg] = *(const float2*)(xb2 + (size_t)jk * F);
        }

        // 3b: h in packed f16 A-layout + MFMA (acc pre-loaded with b2)
        f32x16 acc0, acc1;
#pragma unroll
        for (int r = 0; r < 16; ++r) { acc0[r] = b2v.x; acc1[r] = b2v.y; }

        h2 rxp = { (_Float16)rx[i], (_Float16)rx[i] };
        h2 ryp = { (_Float16)ry[i], (_Float16)ry[i] };
        h2 rzp = { (_Float16)rz[i], (_Float16)rz[i] };

#pragma unroll
        for (int t = 0; t < 4; ++t) {
            h8 af;
#pragma unroll
            for (int jj = 0; jj < 4; ++jj) {
                const int g2 = 8 * t + 4 * hf + jj;              // g-pair index
                const h8 w = *(const h8*)&w1p[g2][0];            // b128 broadcast
                const h2 wx = __builtin_shufflevector(w, w, 0, 1);
                const h2 wy = __builtin_shufflevector(w, w, 2, 3);
                const h2 wz = __builtin_shufflevector(w, w, 4, 5);
                const h2 bb = __builtin_shufflevector(w, w, 6, 7);
                h2 hv = bb + rxp * wx;                           // v_pk_fma_f16 chain
                hv = hv + ryp * wy;
                hv = hv + rzp * wz;
                hv = __builtin_elementwise_max(hv, hv * c01);    // leaky_relu(0.1)
                af[2 * jj]     = hv[0];
                af[2 * jj + 1] = hv[1];
            }
            acc0 = __builtin_amdgcn_mfma_f32_32x32x16_f16(af, bfrag[t][0], acc0, 0, 0, 0);
            acc1 = __builtin_amdgcn_mfma_f32_32x32x16_f16(af, bfrag[t][1], acc1, 0, 0, 0);
        }

        // 3c: epilogue — acc already includes b2; weighted sum over this half's rows
        float s0 = 0.f, s1 = 0.f;
#pragma unroll
        for (int reg = 0; reg < 16; ++reg) {
            s0 = fmaf(acc0[reg], xv[reg].x, s0);
            s1 = fmaf(acc1[reg], xv[reg].y, s1);
        }
        s0 += __shfl_xor(s0, 32);                                // merge k-halves
        s1 += __shfl_xor(s1, 32);
        if (hf == 0)
            *(float2*)(out + (size_t)p * F + 2 * m) = make_float2(s0, s1);
    }
}

extern "C" void kernel_launch(void* const* d_in, const int* in_sizes, int n_in,
                              void* d_out, int out_size, void* d_ws, size_t ws_size,
                              hipStream_t stream) {
    const float* x   = (const float*)d_in[0];
    const float* pos = (const float*)d_in[1];
    const int*   idx = (const int*)  d_in[2];
    const float* W1  = (const float*)d_in[3];
    const float* b1  = (const float*)d_in[4];
    const float* W2  = (const float*)d_in[5];
    const float* b2  = (const float*)d_in[6];
    float* out = (float*)d_out;

    dim3 grid((BATCH * NPTS) / (4 * WPTS));   // 4 waves/block, WPTS points/wave
    dim3 block(256);
    pointconv_mfma<<<grid, block, 0, stream>>>(x, pos, idx, W1, b1, W2, b2, out);
}

// Round 5
// 144.996 us; speedup vs baseline: 2.3688x; 2.3688x over previous
//
#include <hip/hip_runtime.h>

// PointConv: B=4, N=16384, K=32, F=64
// out[p,f] = sum_k ( lrelu(rel(p,k) @ W1 + b1) @ W2 + b2 )[f] * x[idx[p,k], f]
//
// Round 5: round-4 ideas with register pressure actually controlled.
//  - #pragma unroll 1 point loop (no cross-point hoist; live set ~110 regs)
//  - __launch_bounds__(256,2): generous cap, compiler must not spill to quota
//  - manual 1-deep pipeline: next point's idx+pos (rel_pos chain) prefetched
//    during current point's MFMA phase
//  - scalar rowp[const] idx loads (s_load_dwordx8), no js[] array
//  - conflict-free W2 fragment LDS layout [hf][t][c][m][j] (lanes hit
//    consecutive 16B blocks)
//  - f16 packed h (v_pk_fma_f16), v_mfma_f32_32x32x16_f16, f-interleaved
//    tiles (tile c <-> f=2m+c) -> float2 x-gather + float2 out store
//  - b2 folded into accumulator init

#define NPTS   16384
#define KNB    32
#define F      64
#define BATCH  4
#define LOG2N  14
#define WPTS   8

typedef _Float16 h2     __attribute__((ext_vector_type(2)));
typedef _Float16 h8     __attribute__((ext_vector_type(8)));
typedef float    f32x16 __attribute__((ext_vector_type(16)));

__global__ __launch_bounds__(256, 2) void pointconv_mfma(
    const float* __restrict__ x,
    const float* __restrict__ pos,
    const int*   __restrict__ idx,
    const float* __restrict__ W1,
    const float* __restrict__ b1,
    const float* __restrict__ W2,
    const float* __restrict__ b2,
    float*       __restrict__ out)
{
    // w1p[g/2] = {wx,wx', wy,wy', wz,wz', b1,b1'} for g-pair (f16)
    __shared__ __align__(16) _Float16 w1p[32][8];
    // w2f[hf][t][c][m][j] = f16(W2[16t+8hf+j][2m+c]) — fragment-ordered,
    // lanes read consecutive 16B blocks -> conflict-free ds_read_b128
    __shared__ __align__(16) _Float16 w2f[2][4][2][32][8];

    const int tid = threadIdx.x;
    if (tid < 32) {
        const int g = 2 * tid;
        w1p[tid][0] = (_Float16)W1[0 * F + g]; w1p[tid][1] = (_Float16)W1[0 * F + g + 1];
        w1p[tid][2] = (_Float16)W1[1 * F + g]; w1p[tid][3] = (_Float16)W1[1 * F + g + 1];
        w1p[tid][4] = (_Float16)W1[2 * F + g]; w1p[tid][5] = (_Float16)W1[2 * F + g + 1];
        w1p[tid][6] = (_Float16)b1[g];         w1p[tid][7] = (_Float16)b1[g + 1];
    }
#pragma unroll
    for (int r = 0; r < 16; ++r) {             // 4096 elems, coalesced global read
        const int e = r * 256 + tid;           // e = g*64 + f
        const int g = e >> 6, f = e & 63;
        w2f[(g >> 3) & 1][g >> 4][f & 1][f >> 1][g & 7] = (_Float16)W2[e];
    }
    __syncthreads();

    const int lane = tid & 63;
    const int wv   = tid >> 6;
    const int m    = lane & 31;   // MFMA row (neighbor slot) / f-pair index
    const int hf   = lane >> 5;   // k-half of A/B fragments

    // B fragments: one conflict-free b128 each
    h8 bfrag[4][2];
#pragma unroll
    for (int t = 0; t < 4; ++t)
#pragma unroll
        for (int c = 0; c < 2; ++c)
            bfrag[t][c] = *(const h8*)&w2f[hf][t][c][m][0];

    const float2 b2v = *(const float2*)(b2 + 2 * m);

    const int p0   = (blockIdx.x * 4 + wv) * WPTS;
    const int p0_s = __builtin_amdgcn_readfirstlane(p0);
    const int base = (p0_s >> LOG2N) << LOG2N;                     // b*N
    const float* __restrict__ xb2 = x + (size_t)base * F + 2 * m;  // lane gather base

    // ---- prologue: rel_pos for point i=0 (lane owns neighbor m) ----
    float rx, ry, rz;
    {
        const int jm = idx[p0_s * KNB + m];
        const int nr = base + jm;
        rx = pos[p0_s * 3 + 0] - pos[nr * 3 + 0];
        ry = pos[p0_s * 3 + 1] - pos[nr * 3 + 1];
        rz = pos[p0_s * 3 + 2] - pos[nr * 3 + 2];
    }

    const h2 c01 = { (_Float16)0.1f, (_Float16)0.1f };

#pragma unroll 1
    for (int i = 0; i < WPTS; ++i) {
        const int p_s = p0_s + i;                       // wave-uniform (SGPR)
        const int* __restrict__ rowp = idx + (size_t)p_s * KNB;

        // ---- x-gather: rows via scalar loads, one float2 per reg ----
        float2 xv[16];
#pragma unroll
        for (int reg = 0; reg < 16; ++reg) {
            const int rA  = (reg & 3) + ((reg >> 2) << 3);
            const int jlo = rowp[rA];                   // s_load (uniform)
            const int jhi = rowp[rA + 4];               // s_load (uniform)
            const int jk  = hf ? jhi : jlo;             // v_cndmask
            xv[reg] = *(const float2*)(xb2 + (size_t)jk * F);
        }

        // ---- prefetch next point's rel_pos (hidden under MFMA phase) ----
        float rxn = 0.f, ryn = 0.f, rzn = 0.f;
        if (i + 1 < WPTS) {
            const int jmn = idx[(p_s + 1) * KNB + m];
            const int nr  = base + jmn;
            rxn = pos[(p_s + 1) * 3 + 0] - pos[nr * 3 + 0];
            ryn = pos[(p_s + 1) * 3 + 1] - pos[nr * 3 + 1];
            rzn = pos[(p_s + 1) * 3 + 2] - pos[nr * 3 + 2];
        }

        // ---- h in packed f16 A-layout + MFMA (acc preloaded with b2) ----
        f32x16 acc0, acc1;
#pragma unroll
        for (int r = 0; r < 16; ++r) { acc0[r] = b2v.x; acc1[r] = b2v.y; }

        const h2 rxp = { (_Float16)rx, (_Float16)rx };
        const h2 ryp = { (_Float16)ry, (_Float16)ry };
        const h2 rzp = { (_Float16)rz, (_Float16)rz };

#pragma unroll
        for (int t = 0; t < 4; ++t) {
            h8 af;
#pragma unroll
            for (int jj = 0; jj < 4; ++jj) {
                const int g2 = 8 * t + 4 * hf + jj;              // g-pair index
                const h8 w = *(const h8*)&w1p[g2][0];            // b128, 2 addrs/wave
                const h2 wx = __builtin_shufflevector(w, w, 0, 1);
                const h2 wy = __builtin_shufflevector(w, w, 2, 3);
                const h2 wz = __builtin_shufflevector(w, w, 4, 5);
                const h2 bb = __builtin_shufflevector(w, w, 6, 7);
                h2 hv = bb + rxp * wx;                           // v_pk_fma_f16
                hv = hv + ryp * wy;
                hv = hv + rzp * wz;
                hv = __builtin_elementwise_max(hv, hv * c01);    // leaky_relu(0.1)
                af[2 * jj]     = hv[0];
                af[2 * jj + 1] = hv[1];
            }
            acc0 = __builtin_amdgcn_mfma_f32_32x32x16_f16(af, bfrag[t][0], acc0, 0, 0, 0);
            acc1 = __builtin_amdgcn_mfma_f32_32x32x16_f16(af, bfrag[t][1], acc1, 0, 0, 0);
        }

        // ---- epilogue: weighted sum over this half's 16 rows, merge halves ----
        float s0 = 0.f, s1 = 0.f;
#pragma unroll
        for (int reg = 0; reg < 16; ++reg) {
            s0 = fmaf(acc0[reg], xv[reg].x, s0);
            s1 = fmaf(acc1[reg], xv[reg].y, s1);
        }
        s0 += __shfl_xor(s0, 32);
        s1 += __shfl_xor(s1, 32);
        if (hf == 0)
            *(float2*)(out + (size_t)p_s * F + 2 * m) = make_float2(s0, s1);

        rx = rxn; ry = ryn; rz = rzn;
    }
}

extern "C" void kernel_launch(void* const* d_in, const int* in_sizes, int n_in,
                              void* d_out, int out_size, void* d_ws, size_t ws_size,
                              hipStream_t stream) {
    const float* x   = (const float*)d_in[0];
    const float* pos = (const float*)d_in[1];
    const int*   idx = (const int*)  d_in[2];
    const float* W1  = (const float*)d_in[3];
    const float* b1  = (const float*)d_in[4];
    const float* W2  = (const float*)d_in[5];
    const float* b2  = (const float*)d_in[6];
    float* out = (float*)d_out;

    dim3 grid((BATCH * NPTS) / (4 * WPTS));   // 4 waves/block, WPTS points/wave
    dim3 block(256);
    pointconv_mfma<<<grid, block, 0, stream>>>(x, pos, idx, W1, b1, W2, b2, out);
}